// Round 12
// baseline (5788.832 us; speedup 1.0000x reference)
//
#include <hip/hip_runtime.h>
#include <hip/hip_bf16.h>

// BiLSTM-CRF loss, MI355X. B=64 T=512 V=30000 E=256 H=512 C=9.
// Round 12: R10 (swapped-operand MFMA, packed write-once exchange, flag
// protocol) with the producer ACK removed from the inter-wave chain:
// flag store issues immediately after data stores (no vmcnt between);
// consumers still gate data loads on the flag (no payload speculation),
// and NaN-sentinel validation + bounded per-packet reload backstops the
// rare flag-overtakes-data completion race. Speculative flag prefetch
// overlaps detection with x-MFMA. Own store-ack migrates into next step's
// WAITV(0), overlapped with flag propagation.

using short8 = __attribute__((ext_vector_type(8))) short;   // 8 x bf16 bits
using f32x4  = __attribute__((ext_vector_type(4))) float;
using i32x4  = __attribute__((ext_vector_type(4))) int;

#define TT 512
#define BB 64
#define SENTW ((int)0x7FC07FC0)   // two bf16 NaNs; finite h never encodes this

__device__ __forceinline__ unsigned short f2bf(float f) {
  unsigned int u = __builtin_bit_cast(unsigned int, f);
  u += 0x7FFFu + ((u >> 16) & 1u);           // RNE
  return (unsigned short)(u >> 16);
}
__device__ __forceinline__ float bf2f(short s) {
  unsigned int u = ((unsigned int)(unsigned short)s) << 16;
  return __builtin_bit_cast(float, u);
}
__device__ __forceinline__ float fast_rcp(float x) { return __builtin_amdgcn_rcpf(x); }
__device__ __forceinline__ float sigmoid_f(float x) { return fast_rcp(1.f + __expf(-x)); }
__device__ __forceinline__ float tanh_f(float x) {
  float e = __expf(-2.f * fabsf(x));
  float r = (1.f - e) * fast_rcp(1.f + e);
  return copysignf(r, x);
}

// ---- coherence-point ops (sc0 sc1) ----
__device__ __forceinline__ i32x4 load16_sc(const void* p) {      // no wait
  i32x4 r;
  asm volatile("global_load_dwordx4 %0, %1, off sc0 sc1" : "=v"(r) : "v"(p));
  return r;
}
__device__ __forceinline__ i32x4 load16_sc_wait(const void* p) { // self-waiting
  i32x4 r;
  asm volatile("global_load_dwordx4 %0, %1, off sc0 sc1\n\ts_waitcnt vmcnt(0)"
               : "=v"(r) : "v"(p) : "memory");
  return r;
}
__device__ __forceinline__ void store4_sc(void* p, unsigned int v) {
  asm volatile("global_store_dword %0, %1, off sc0 sc1" :: "v"(p), "v"(v) : "memory");
}
#define WAITV(n) do { asm volatile("s_waitcnt vmcnt(" #n ")" ::: "memory"); \
                      __builtin_amdgcn_sched_barrier(0); } while (0)

// ---------------- K0a: pack LSTM + FC weights to bf16 (A-fragment rows) -----
// Row n in [0,64) of slice bid (d=bid&1, sl=bid>>1):
//   nt=n>>5, mi=(n>>4)&1, u=(n>>2)&3, g=n&3
//   physical weight row r = g*512 + sl*16 + nt*8 + 2*u + mi
__global__ void pack_weights(const float* __restrict__ Wih_f, const float* __restrict__ Whh_f,
                             const float* __restrict__ Wih_b, const float* __restrict__ Whh_b,
                             const float* __restrict__ Wfc,
                             short* __restrict__ WpackX, short* __restrict__ WpackH,
                             short* __restrict__ WfcPack) {
  const int bid = blockIdx.x;
  const int d = bid & 1, sl = bid >> 1;
  const float* Wih = d ? Wih_b : Wih_f;
  const float* Whh = d ? Whh_b : Whh_f;
  for (int idx = threadIdx.x; idx < 64 * 256; idx += 256) {
    int n = idx >> 8, k = idx & 255;
    int nt = n >> 5, mi = (n >> 4) & 1, u = (n >> 2) & 3, g = n & 3;
    int r = g * 512 + sl * 16 + nt * 8 + 2 * u + mi;
    WpackX[((size_t)bid * 64 + n) * 256 + k] = (short)f2bf(Wih[(size_t)r * 256 + k]);
  }
  for (int idx = threadIdx.x; idx < 64 * 512; idx += 256) {
    int n = idx >> 9, k = idx & 511;
    int nt = n >> 5, mi = (n >> 4) & 1, u = (n >> 2) & 3, g = n & 3;
    int r = g * 512 + sl * 16 + nt * 8 + 2 * u + mi;
    WpackH[((size_t)bid * 64 + n) * 512 + k] = (short)f2bf(Whh[(size_t)r * 512 + k]);
  }
  if (bid == 0) {
    for (int idx = threadIdx.x; idx < 16 * 1024; idx += 256) {
      int c = idx >> 10, k = idx & 1023;
      WfcPack[idx] = (c < 9) ? (short)f2bf(Wfc[c * 1024 + k]) : (short)0;
    }
  }
}

// ---------------- K0b: gather embeddings into B-fragment packets ------------
__global__ void pack_x(const int* __restrict__ x, const float* __restrict__ emb,
                       short* __restrict__ xpack) {
  int gid = blockIdx.x * 256 + threadIdx.x;     // < 1048576
  int lane = gid & 63;
  int kc = (gid >> 6) & 7;
  int mt = (gid >> 9) & 3;
  int t  = gid >> 11;
  int b  = mt * 16 + (lane & 15);
  int k0 = kc * 32 + (lane >> 4) * 8;
  int vid = x[b * TT + t];
  const float* e = emb + (size_t)vid * 256 + k0;
  short8 v;
#pragma unroll
  for (int i = 0; i < 8; ++i) v[i] = (short)f2bf(e[i]);
  *reinterpret_cast<short8*>(xpack + (size_t)gid * 8) = v;
}

// ---------------- K0c: zero flags + sentinel-fill hexch ---------------------
__global__ void init_state(int* __restrict__ flags) {
  flags[threadIdx.x] = 0;                       // 256 flags
}
__global__ void sentinel_fill(i32x4* __restrict__ p) {   // 64 MB = 4,194,304 x 16B
  int gid = blockIdx.x * 256 + threadIdx.x;
  const i32x4 v = {SENTW, SENTW, SENTW, SENTW};
  for (int i = gid; i < 4194304; i += 4096 * 256) p[i] = v;
}

// ---------------- K1: persistent BiLSTM (swapped MFMA, deferred-ack) --------
// 64 WGs x 256 thr. WG: d=bid&1, sl=bid>>1 owns 16 units x 4 gates.
// Wave (mtb=wv&1, nt=wv>>1): batch rows [mtb*32,+32) x 8 units.
// hexch packet layout per (d,t): [mtb][kc(16)][ni(2)][lane(64)] x 16B = 64KB,
// slot l = h[batch mtb*32+ni*16+(l&15)][units kc*32+(l>>4)*8 .. +8].
// Per step: speculative flag-quad load -> x-MFMA -> flag check/poll ->
// 32 packet loads -> per-half validate (NaN sentinel) + MFMA (reload rare)
// -> lane-local gates -> 4B/lane packed stores -> flag store (NO ack).
__launch_bounds__(256, 1)
__global__ void lstm_step_kernel(const short8* __restrict__ xpack,
                                 const short* __restrict__ WpackX,
                                 const short* __restrict__ WpackH,
                                 short* __restrict__ hexch,   // [2][512] x 64KB
                                 int* __restrict__ flags,     // [4][64]
                                 const float* __restrict__ b_f,
                                 const float* __restrict__ b_b,
                                 const int* __restrict__ seq_len) {
  const int bid = blockIdx.x;
  const int d = bid & 1;
  const int sl = bid >> 1;
  const int tid = threadIdx.x;
  const int wv = tid >> 6;
  const int lane = tid & 63;
  const int l15 = lane & 15;
  const int lhi = lane >> 4;
  const int mtb = wv & 1;          // wave's row half
  const int nt = wv >> 1;          // wave's 8-unit group
  const int mbase = mtb * 32;
  const int nbase = nt * 32;
  const int ubase = sl * 16 + nt * 8;            // wave's 8-unit base
  const int kc_w  = ubase >> 5;                  // packet kc of this wave's units
  const int lhi_c = (ubase >> 3) & 3;            // packet k-slice of its units

  // Wih + Whh A-fragments, register-resident for the whole kernel.
  short8 bfx[2][8];
#pragma unroll
  for (int mi = 0; mi < 2; ++mi)
#pragma unroll
    for (int kc = 0; kc < 8; ++kc)
      bfx[mi][kc] = *reinterpret_cast<const short8*>(
          WpackX + ((size_t)bid * 64 + nbase + mi * 16 + l15) * 256 + kc * 32 + lhi * 8);
  short8 bfh[2][16];
#pragma unroll
  for (int mi = 0; mi < 2; ++mi)
#pragma unroll
    for (int kc = 0; kc < 16; ++kc)
      bfh[mi][kc] = *reinterpret_cast<const short8*>(
          WpackH + ((size_t)bid * 64 + nbase + mi * 16 + l15) * 512 + kc * 32 + lhi * 8);

  const float* bias = d ? b_b : b_f;
  float b4[2][4];
#pragma unroll
  for (int mi = 0; mi < 2; ++mi) {
    int jg = ubase + 2 * lhi + mi;               // this lane's unit (per mi)
#pragma unroll
    for (int g = 0; g < 4; ++g) b4[mi][g] = bias[g * 512 + jg];
  }
  int Lr[2];
#pragma unroll
  for (int ni = 0; ni < 2; ++ni)
    Lr[ni] = seq_len[mbase + ni * 16 + l15];     // this lane's batch row
  float cst[2][2] = {{0.f, 0.f}, {0.f, 0.f}};
  float hst[2][2] = {{0.f, 0.f}, {0.f, 0.f}};

  int* fl_grp  = flags + (d * 2 + mtb) * 64;
  int* fl_mine = fl_grp + (sl * 2 + nt);
  const int* fl_quad = fl_grp + (lane & 15) * 4;   // packed dwordx4 poll

#define HADDR16(kc, ni) (hp16 + ((mtb * 16 + (kc)) * 2 + (ni)) * 64 + lane)
#define VALR(klo, khi, bv)                                                      \
  do { bv = 0u;                                                                 \
    _Pragma("unroll")                                                           \
    for (int k = (klo); k < (khi); ++k) {                                       \
      i32x4 v = hbuf[k];                                                        \
      bool bb = (v[0] == SENTW) | (v[1] == SENTW) |                             \
                (v[2] == SENTW) | (v[3] == SENTW);                              \
      bv |= (bb ? (1u << k) : 0u);                                              \
    }                                                                           \
  } while (0)
#define MFMA_R(kclo, kchi)                                                      \
  _Pragma("unroll")                                                             \
  for (int kc = (kclo); kc < (kchi); ++kc)                                      \
    _Pragma("unroll")                                                           \
    for (int ni = 0; ni < 2; ++ni) {                                            \
      short8 bfrag = __builtin_bit_cast(short8, hbuf[kc * 2 + ni]);             \
      _Pragma("unroll")                                                         \
      for (int mi = 0; mi < 2; ++mi)                                            \
        acc[mi][ni] = __builtin_amdgcn_mfma_f32_16x16x32_bf16(bfh[mi][kc], bfrag, acc[mi][ni], 0, 0, 0); \
    }
#define RELOADR(klo, khi, bv)                                                   \
  do { int _tr = 0;                                                             \
    while (__any(bv != 0u) && _tr++ < (1 << 16)) {                              \
      _Pragma("unroll")                                                         \
      for (int k = (klo); k < (khi); ++k)                                       \
        if (bv & (1u << k)) hbuf[k] = load16_sc(HADDR16(k >> 1, k & 1));        \
      WAITV(0);                                                                 \
      VALR(klo, khi, bv);                                                       \
    }                                                                           \
  } while (0)

  for (int s = 0; s < TT; ++s) {
    const int t = d ? (TT - 1 - s) : s;
    f32x4 acc[2][2];
#pragma unroll
    for (int mi = 0; mi < 2; ++mi)
#pragma unroll
      for (int ni = 0; ni < 2; ++ni) acc[mi][ni] = (f32x4){0.f, 0.f, 0.f, 0.f};

    // ---- Phase P: speculative flag-quad load (detect overlaps x-MFMA) ----
    i32x4 fq;
    if (s > 0) fq = load16_sc(fl_quad);

    // ---- Phase A: Wih(A) x x(B)  (no sequential dependency) ----
    const short8* xp = xpack + (size_t)t * 2048;
#pragma unroll
    for (int kc = 0; kc < 8; ++kc) {
      short8 bf[2];
#pragma unroll
      for (int ni = 0; ni < 2; ++ni)
        bf[ni] = xp[((mtb * 2 + ni) * 8 + kc) * 64 + lane];
#pragma unroll
      for (int mi = 0; mi < 2; ++mi)
#pragma unroll
        for (int ni = 0; ni < 2; ++ni)
          acc[mi][ni] = __builtin_amdgcn_mfma_f32_16x16x32_bf16(bfx[mi][kc], bf[ni], acc[mi][ni], 0, 0, 0);
    }

    if (s > 0) {
      // ---- Phase B: flag gate (speculative result first, then poll) ----
      // WAITV(0) also drains last step's data/flag stores: the store-ack
      // now overlaps flag propagation + x-MFMA instead of preceding the
      // flag publish (deferred ack).
      WAITV(0);
      bool ok = (fq[0] >= s) & (fq[1] >= s) & (fq[2] >= s) & (fq[3] >= s);
      if (!__all(ok)) {
        int vtries = 0;
        while (true) {
          i32x4 f = load16_sc_wait(fl_quad);
          ok = (f[0] >= s) & (f[1] >= s) & (f[2] >= s) & (f[3] >= s);
          if (__all(ok)) break;
          __builtin_amdgcn_s_sleep(1);
          if (++vtries > (1 << 18)) break;     // anti-hang valve
        }
      }
      __builtin_amdgcn_sched_barrier(0);

      // ---- Phase C: 32 packet loads; per-half validate + MFMA ----
      const int tprev = d ? (t + 1) : (t - 1);
      const i32x4* hp16 = (const i32x4*)(hexch + ((size_t)d * TT + tprev) * 32768);
      i32x4 hbuf[32];
#pragma unroll
      for (int kc = 0; kc < 16; ++kc)
#pragma unroll
        for (int ni = 0; ni < 2; ++ni)
          hbuf[kc * 2 + ni] = load16_sc(HADDR16(kc, ni));
      WAITV(16);                                // first 16 packets (kc 0..7)
      unsigned bad;
      VALR(0, 16, bad);
      if (!__any(bad != 0u)) {                  // fast path
        __builtin_amdgcn_sched_barrier(0);
        MFMA_R(0, 8);
        WAITV(0);                               // second 16 packets
        VALR(16, 32, bad);
        if (__any(bad != 0u)) RELOADR(16, 32, bad);
        __builtin_amdgcn_sched_barrier(0);
        MFMA_R(8, 16);
      } else {                                  // rare: race in first half
        WAITV(0);
        unsigned bad2;
        VALR(16, 32, bad2);
        bad |= bad2;
        RELOADR(0, 32, bad);
        __builtin_amdgcn_sched_barrier(0);
        MFMA_R(0, 16);
      }
    }

    // ---- Phase D: lane-local gates (reg=gate), state update, 4B stores ----
    short* hx = hexch + ((size_t)d * TT + t) * 32768;
#pragma unroll
    for (int ni = 0; ni < 2; ++ni) {
      const bool m = (t < Lr[ni]);
      unsigned short hnb[2];
#pragma unroll
      for (int mi = 0; mi < 2; ++mi) {
        f32x4 A = acc[mi][ni];
        float gi = A[0] + b4[mi][0];
        float gf = A[1] + b4[mi][1];
        float gg = A[2] + b4[mi][2];
        float go = A[3] + b4[mi][3];
        float si = sigmoid_f(gi), sf = sigmoid_f(gf), so = sigmoid_f(go);
        float ct = sf * cst[mi][ni] + si * tanh_f(gg);
        float ht = so * tanh_f(ct);
        float cn = m ? ct : cst[mi][ni];
        float hn = m ? ht : hst[mi][ni];
        cst[mi][ni] = cn;
        hst[mi][ni] = hn;
        hnb[mi] = f2bf(hn);                     // frozen carry (= history when t<L)
      }
      unsigned int up = ((unsigned int)hnb[1] << 16) | hnb[0];
      store4_sc((char*)hx
                    + (size_t)(((mtb * 16 + kc_w) * 2 + ni) * 64 + lhi_c * 16 + l15) * 16
                    + lhi * 4,
                up);
    }

    // ---- Phase E: flag publish immediately (deferred ack; sentinel
    //      validation on the consumer side backstops the ordering race) ----
    if (lane == 0) {
      int sv = s + 1;
      asm volatile("global_store_dword %0, %1, off sc0 sc1"
                   :: "v"(fl_mine), "v"(sv) : "memory");
    }
  }
#undef HADDR16
#undef VALR
#undef MFMA_R
#undef RELOADR
}

// ---------------- K2: emission logits = [hf|hb] @ Wfc^T via MFMA ------------
// Reads fragment-packed hexch (frozen values at t>=L are masked by the CRF).
__launch_bounds__(256)
__global__ void emis_kernel(const short* __restrict__ hexch,
                            const short* __restrict__ WfcPack,
                            float* __restrict__ logits) {
  __shared__ short wfc[16 * 1032];             // padded stride vs bank conflicts
  const int tid = threadIdx.x;
  for (int idx = tid; idx < 2048; idx += 256) {
    int n = idx >> 7, c8 = idx & 127;
    short8 v = *reinterpret_cast<const short8*>(WfcPack + n * 1024 + c8 * 8);
    *reinterpret_cast<short8*>(&wfc[n * 1032 + c8 * 8]) = v;
  }
  __syncthreads();
  const int wv = tid >> 6, lane = tid & 63;
  const int l15 = lane & 15, lhi = lane >> 4;
  const i32x4* hx = (const i32x4*)hexch;
#pragma unroll
  for (int mt2 = 0; mt2 < 2; ++mt2) {
    int m = (blockIdx.x * 4 + wv) * 2 + mt2;
    int r0 = m * 16;                           // r = t*64 + b ; block has fixed t
    int t   = r0 >> 6;
    int mtb = (r0 >> 5) & 1;
    int ti  = (r0 >> 4) & 1;
    f32x4 acc = (f32x4){0.f, 0.f, 0.f, 0.f};
#pragma unroll
    for (int kc = 0; kc < 32; ++kc) {
      int dd  = kc >> 4;                       // 0 = forward half, 1 = backward
      int kcf = kc & 15;
      short8 a = __builtin_bit_cast(short8,
          hx[((size_t)dd * TT + t) * 4096 + ((mtb * 16 + kcf) * 2 + ti) * 64
             + lhi * 16 + l15]);
      short8 b = *reinterpret_cast<const short8*>(&wfc[l15 * 1032 + kc * 32 + lhi * 8]);
      acc = __builtin_amdgcn_mfma_f32_16x16x32_bf16(a, b, acc, 0, 0, 0);
    }
    int c = l15;
    if (c < 9) {
#pragma unroll
      for (int reg = 0; reg < 4; ++reg) {
        int rr = r0 + lhi * 4 + reg;
        int b = rr & 63, tt = rr >> 6;
        logits[((size_t)b * TT + tt) * 9 + c] = acc[reg];
      }
    }
  }
}

// ---------------- K3: CRF numerator + forward algorithm per batch -----------
__global__ void crf_kernel(const float* __restrict__ logits, const int* __restrict__ y,
                           const int* __restrict__ seq_len, const float* __restrict__ start_t,
                           const float* __restrict__ end_t, const float* __restrict__ trans,
                           float* __restrict__ partials) {
  const int b = blockIdx.x;
  const int lane = threadIdx.x;          // 64
  const float* lg = logits + (size_t)b * TT * 9;
  const int* yb = y + b * TT;
  const int L = seq_len[b];

  float acc = 0.f;
  for (int t = lane; t < TT; t += 64) {
    if (t < L) {
      float mx = lg[t * 9];
      for (int c = 1; c < 9; ++c) mx = fmaxf(mx, lg[t * 9 + c]);
      float se = 0.f;
      for (int c = 0; c < 9; ++c) se += __expf(lg[t * 9 + c] - mx);
      float lse = mx + __logf(se);
      int yt = yb[t];
      acc += lg[t * 9 + yt] - lse;
      if (t >= 1) acc += trans[yb[t - 1] * 9 + yt];
    }
  }
#pragma unroll
  for (int off = 32; off >= 1; off >>= 1) acc += __shfl_down(acc, off, 64);

  const int c = (lane < 9) ? lane : 0;
  float score;
  {
    float mx = lg[0];
    for (int cc = 1; cc < 9; ++cc) mx = fmaxf(mx, lg[cc]);
    float se = 0.f;
    for (int cc = 0; cc < 9; ++cc) se += __expf(lg[cc] - mx);
    score = start_t[c] + lg[c] - (mx + __logf(se));
  }
  float tr[9];
#pragma unroll
  for (int cc = 0; cc < 9; ++cc) tr[cc] = trans[cc * 9 + c];
  for (int t = 1; t < L; ++t) {
    const float* lt = lg + t * 9;
    float mx2 = lt[0];
    for (int cc = 1; cc < 9; ++cc) mx2 = fmaxf(mx2, lt[cc]);
    float se2 = 0.f;
    for (int cc = 0; cc < 9; ++cc) se2 += __expf(lt[cc] - mx2);
    float em = lt[c] - (mx2 + __logf(se2));
    float vv[9];
    float mx = -1e30f;
#pragma unroll
    for (int cc = 0; cc < 9; ++cc) {
      float sp = __shfl(score, cc, 64);
      vv[cc] = sp + tr[cc];
      mx = fmaxf(mx, vv[cc]);
    }
    float se = 0.f;
#pragma unroll
    for (int cc = 0; cc < 9; ++cc) se += __expf(vv[cc] - mx);
    score = mx + __logf(se) + em;
  }
  float val = (lane < 9) ? (score + end_t[lane]) : -1e30f;
  float mm = val;
#pragma unroll
  for (int off = 1; off < 64; off <<= 1) mm = fmaxf(mm, __shfl_xor(mm, off, 64));
  float se = (lane < 9) ? __expf(val - mm) : 0.f;
#pragma unroll
  for (int off = 1; off < 64; off <<= 1) se += __shfl_xor(se, off, 64);
  float den = mm + __logf(se);
  if (lane == 0) {
    float num = acc + start_t[yb[0]] + end_t[yb[L - 1]];
    partials[b] = num - den;
  }
}

// ---------------- K4: final reduce ------------------------------------------
__global__ void finalize_kernel(const float* __restrict__ partials, float* __restrict__ out) {
  int l = threadIdx.x;
  float v = partials[l];
#pragma unroll
  for (int off = 32; off >= 1; off >>= 1) v += __shfl_down(v, off, 64);
  if (l == 0) out[0] = -v;
}

extern "C" void kernel_launch(void* const* d_in, const int* in_sizes, int n_in,
                              void* d_out, int out_size, void* d_ws, size_t ws_size,
                              hipStream_t stream) {
  const int*   x     = (const int*)d_in[0];
  const int*   seqln = (const int*)d_in[1];
  const int*   y     = (const int*)d_in[2];
  const float* emb   = (const float*)d_in[3];
  const float* Wih_f = (const float*)d_in[4];
  const float* Whh_f = (const float*)d_in[5];
  const float* b_f   = (const float*)d_in[6];
  const float* Wih_b = (const float*)d_in[7];
  const float* Whh_b = (const float*)d_in[8];
  const float* b_b   = (const float*)d_in[9];
  const float* Wfc   = (const float*)d_in[10];
  const float* st    = (const float*)d_in[11];
  const float* en    = (const float*)d_in[12];
  const float* trans = (const float*)d_in[13];
  float* out = (float*)d_out;

  char* ws = (char*)d_ws;                         // total required ~91.4 MB
  short* WpackX   = (short*)(ws + 0);             // 2,097,152
  short* WpackH   = (short*)(ws + 2097152);       // 4,194,304
  short* WfcPack  = (short*)(ws + 6291456);       //    32,768
  short* xpack    = (short*)(ws + 6324224);       // 16,777,216
  int*   flags    = (int*)  (ws + 23101440);      //     1,024
  float* partials = (float*)(ws + 23102464);      //       256
  float* logits   = (float*)(ws + 23102720);      // 1,179,648
  short* hexch    = (short*)(ws + 24282368);      // 67,108,864 -> end 91,391,232

  pack_weights<<<64, 256, 0, stream>>>(Wih_f, Whh_f, Wih_b, Whh_b, Wfc,
                                       WpackX, WpackH, WfcPack);
  pack_x<<<4096, 256, 0, stream>>>(x, emb, xpack);
  init_state<<<1, 256, 0, stream>>>(flags);
  sentinel_fill<<<4096, 256, 0, stream>>>((i32x4*)hexch);
  lstm_step_kernel<<<64, 256, 0, stream>>>((const short8*)xpack, WpackX, WpackH,
                                           hexch, flags, b_f, b_b, seqln);
  emis_kernel<<<256, 256, 0, stream>>>(hexch, WfcPack, logits);
  crf_kernel<<<64, 64, 0, stream>>>(logits, y, seqln, st, en, trans, partials);
  finalize_kernel<<<1, 64, 0, stream>>>(partials, out);
}

// Round 13
// 3239.777 us; speedup vs baseline: 1.7868x; 1.7868x over previous
//
#include <hip/hip_runtime.h>
#include <hip/hip_bf16.h>

// BiLSTM-CRF loss, MI355X. B=64 T=512 V=30000 E=256 H=512 C=9.
// Round 13: restore the Round-10 champion (3244 us total, 5.9 us/step).
// Swapped-operand MFMA (weights as A, h/x as B): each lane's 4 acc regs hold
// the 4 gates of ONE unit for ONE batch row -> zero-shuffle epilogue and
// coalesced 4B/lane h-stores (contiguous 256B per wave per tile).
// Exchange = write-once fragment-packed hexch + dense sc0sc1 flags,
// quad-poll, vmcnt-ack before flag publish. hexch doubles as emission input.

using short8 = __attribute__((ext_vector_type(8))) short;   // 8 x bf16 bits
using f32x4  = __attribute__((ext_vector_type(4))) float;
using i32x4  = __attribute__((ext_vector_type(4))) int;

#define TT 512
#define BB 64

__device__ __forceinline__ unsigned short f2bf(float f) {
  unsigned int u = __builtin_bit_cast(unsigned int, f);
  u += 0x7FFFu + ((u >> 16) & 1u);           // RNE
  return (unsigned short)(u >> 16);
}
__device__ __forceinline__ float bf2f(short s) {
  unsigned int u = ((unsigned int)(unsigned short)s) << 16;
  return __builtin_bit_cast(float, u);
}
__device__ __forceinline__ float fast_rcp(float x) { return __builtin_amdgcn_rcpf(x); }
__device__ __forceinline__ float sigmoid_f(float x) { return fast_rcp(1.f + __expf(-x)); }
__device__ __forceinline__ float tanh_f(float x) {
  float e = __expf(-2.f * fabsf(x));
  float r = (1.f - e) * fast_rcp(1.f + e);
  return copysignf(r, x);
}

// ---- coherence-point ops (sc0 sc1) ----
__device__ __forceinline__ i32x4 load16_sc(const void* p) {      // no wait
  i32x4 r;
  asm volatile("global_load_dwordx4 %0, %1, off sc0 sc1" : "=v"(r) : "v"(p));
  return r;
}
__device__ __forceinline__ i32x4 load16_sc_wait(const void* p) { // self-waiting
  i32x4 r;
  asm volatile("global_load_dwordx4 %0, %1, off sc0 sc1\n\ts_waitcnt vmcnt(0)"
               : "=v"(r) : "v"(p) : "memory");
  return r;
}
__device__ __forceinline__ void store4_sc(void* p, unsigned int v) {
  asm volatile("global_store_dword %0, %1, off sc0 sc1" :: "v"(p), "v"(v) : "memory");
}
#define WAITV(n) do { asm volatile("s_waitcnt vmcnt(" #n ")" ::: "memory"); \
                      __builtin_amdgcn_sched_barrier(0); } while (0)

// ---------------- K0a: pack LSTM + FC weights to bf16 (A-fragment rows) -----
// Row n in [0,64) of slice bid (d=bid&1, sl=bid>>1):
//   nt=n>>5, mi=(n>>4)&1, u=(n>>2)&3, g=n&3
//   physical weight row r = g*512 + sl*16 + nt*8 + 2*u + mi
__global__ void pack_weights(const float* __restrict__ Wih_f, const float* __restrict__ Whh_f,
                             const float* __restrict__ Wih_b, const float* __restrict__ Whh_b,
                             const float* __restrict__ Wfc,
                             short* __restrict__ WpackX, short* __restrict__ WpackH,
                             short* __restrict__ WfcPack) {
  const int bid = blockIdx.x;
  const int d = bid & 1, sl = bid >> 1;
  const float* Wih = d ? Wih_b : Wih_f;
  const float* Whh = d ? Whh_b : Whh_f;
  for (int idx = threadIdx.x; idx < 64 * 256; idx += 256) {
    int n = idx >> 8, k = idx & 255;
    int nt = n >> 5, mi = (n >> 4) & 1, u = (n >> 2) & 3, g = n & 3;
    int r = g * 512 + sl * 16 + nt * 8 + 2 * u + mi;
    WpackX[((size_t)bid * 64 + n) * 256 + k] = (short)f2bf(Wih[(size_t)r * 256 + k]);
  }
  for (int idx = threadIdx.x; idx < 64 * 512; idx += 256) {
    int n = idx >> 9, k = idx & 511;
    int nt = n >> 5, mi = (n >> 4) & 1, u = (n >> 2) & 3, g = n & 3;
    int r = g * 512 + sl * 16 + nt * 8 + 2 * u + mi;
    WpackH[((size_t)bid * 64 + n) * 512 + k] = (short)f2bf(Whh[(size_t)r * 512 + k]);
  }
  if (bid == 0) {
    for (int idx = threadIdx.x; idx < 16 * 1024; idx += 256) {
      int c = idx >> 10, k = idx & 1023;
      WfcPack[idx] = (c < 9) ? (short)f2bf(Wfc[c * 1024 + k]) : (short)0;
    }
  }
}

// ---------------- K0b: gather embeddings into B-fragment packets ------------
// xpack[t][mtile(4)][kc(8)][lane(64)] : lane = (kslice lhi, batch l15).
__global__ void pack_x(const int* __restrict__ x, const float* __restrict__ emb,
                       short* __restrict__ xpack) {
  int gid = blockIdx.x * 256 + threadIdx.x;     // < 1048576
  int lane = gid & 63;
  int kc = (gid >> 6) & 7;
  int mt = (gid >> 9) & 3;
  int t  = gid >> 11;
  int b  = mt * 16 + (lane & 15);
  int k0 = kc * 32 + (lane >> 4) * 8;
  int vid = x[b * TT + t];
  const float* e = emb + (size_t)vid * 256 + k0;
  short8 v;
#pragma unroll
  for (int i = 0; i < 8; ++i) v[i] = (short)f2bf(e[i]);
  *reinterpret_cast<short8*>(xpack + (size_t)gid * 8) = v;
}

// ---------------- K0c: zero flags -------------------------------------------
__global__ void init_state(int* __restrict__ flags) {
  flags[threadIdx.x] = 0;                       // 256 flags
}

// ---------------- K1: persistent flag-synced BiLSTM (swapped MFMA) ----------
// 64 WGs x 256 thr. WG: d=bid&1, sl=bid>>1 owns 16 units x 4 gates.
// Wave (mtb=wv&1, nt=wv>>1): batch rows [mtb*32,+32) x 8 units.
// D = Whh(A) x h(B): D col=lane&15=batch, row=lhi*4+reg -> lane holds gates
// i,f,g,o (reg 0..3) of unit ubase+2*lhi+mi for batch ni*16+l15. No shuffles.
// hexch packet layout per (d,t): [mtb][kc(16)][ni(2)][lane(64)] x 16B = 64KB,
// packet slot l = h[batch mtb*32+ni*16+(l&15)][units kc*32+(l>>4)*8 .. +8].
__launch_bounds__(256, 1)
__global__ void lstm_step_kernel(const short8* __restrict__ xpack,
                                 const short* __restrict__ WpackX,
                                 const short* __restrict__ WpackH,
                                 short* __restrict__ hexch,   // [2][512] x 64KB
                                 int* __restrict__ flags,     // [4][64]
                                 const float* __restrict__ b_f,
                                 const float* __restrict__ b_b,
                                 const int* __restrict__ seq_len) {
  const int bid = blockIdx.x;
  const int d = bid & 1;
  const int sl = bid >> 1;
  const int tid = threadIdx.x;
  const int wv = tid >> 6;
  const int lane = tid & 63;
  const int l15 = lane & 15;
  const int lhi = lane >> 4;
  const int mtb = wv & 1;          // wave's row half
  const int nt = wv >> 1;          // wave's 8-unit group
  const int mbase = mtb * 32;
  const int nbase = nt * 32;
  const int ubase = sl * 16 + nt * 8;            // wave's 8-unit base
  const int kc_w  = ubase >> 5;                  // packet kc of this wave's units
  const int lhi_c = (ubase >> 3) & 3;            // packet k-slice of its units

  // Wih + Whh A-fragments, register-resident for the whole kernel.
  short8 bfx[2][8];
#pragma unroll
  for (int mi = 0; mi < 2; ++mi)
#pragma unroll
    for (int kc = 0; kc < 8; ++kc)
      bfx[mi][kc] = *reinterpret_cast<const short8*>(
          WpackX + ((size_t)bid * 64 + nbase + mi * 16 + l15) * 256 + kc * 32 + lhi * 8);
  short8 bfh[2][16];
#pragma unroll
  for (int mi = 0; mi < 2; ++mi)
#pragma unroll
    for (int kc = 0; kc < 16; ++kc)
      bfh[mi][kc] = *reinterpret_cast<const short8*>(
          WpackH + ((size_t)bid * 64 + nbase + mi * 16 + l15) * 512 + kc * 32 + lhi * 8);

  const float* bias = d ? b_b : b_f;
  float b4[2][4];
#pragma unroll
  for (int mi = 0; mi < 2; ++mi) {
    int jg = ubase + 2 * lhi + mi;               // this lane's unit (per mi)
#pragma unroll
    for (int g = 0; g < 4; ++g) b4[mi][g] = bias[g * 512 + jg];
  }
  int Lr[2];
#pragma unroll
  for (int ni = 0; ni < 2; ++ni)
    Lr[ni] = seq_len[mbase + ni * 16 + l15];     // this lane's batch row
  float cst[2][2] = {{0.f, 0.f}, {0.f, 0.f}};
  float hst[2][2] = {{0.f, 0.f}, {0.f, 0.f}};

  int* fl_grp  = flags + (d * 2 + mtb) * 64;
  int* fl_mine = fl_grp + (sl * 2 + nt);
  const int* fl_quad = fl_grp + (lane & 15) * 4;   // packed dwordx4 poll

  for (int s = 0; s < TT; ++s) {
    const int t = d ? (TT - 1 - s) : s;
    f32x4 acc[2][2];
#pragma unroll
    for (int mi = 0; mi < 2; ++mi)
#pragma unroll
      for (int ni = 0; ni < 2; ++ni) acc[mi][ni] = (f32x4){0.f, 0.f, 0.f, 0.f};

    // ---- Phase A: Wih(A) x x(B)  (no sequential dependency) ----
    const short8* xp = xpack + (size_t)t * 2048;
#pragma unroll
    for (int kc = 0; kc < 8; ++kc) {
      short8 bf[2];
#pragma unroll
      for (int ni = 0; ni < 2; ++ni)
        bf[ni] = xp[((mtb * 2 + ni) * 8 + kc) * 64 + lane];
#pragma unroll
      for (int mi = 0; mi < 2; ++mi)
#pragma unroll
        for (int ni = 0; ni < 2; ++ni)
          acc[mi][ni] = __builtin_amdgcn_mfma_f32_16x16x32_bf16(bfx[mi][kc], bf[ni], acc[mi][ni], 0, 0, 0);
    }

    if (s > 0) {
      // ---- Phase B: poll the 64 producer flags (dwordx4 over dense flags) --
      {
        int vtries = 0;
        while (true) {
          i32x4 f = load16_sc_wait(fl_quad);
          bool ok = (f[0] >= s) & (f[1] >= s) & (f[2] >= s) & (f[3] >= s);
          if (__all(ok)) break;
          __builtin_amdgcn_s_sleep(1);
          if (++vtries > (1 << 18)) break;     // anti-hang valve
        }
      }
      __builtin_amdgcn_sched_barrier(0);

      // ---- Phase C: 32 contiguous 1KB packet loads, counted-vmcnt MFMA ----
      const int tprev = d ? (t + 1) : (t - 1);
      const i32x4* hp16 = (const i32x4*)(hexch + ((size_t)d * TT + tprev) * 32768);
      i32x4 hbuf[32];
#pragma unroll
      for (int kc = 0; kc < 16; ++kc)
#pragma unroll
        for (int ni = 0; ni < 2; ++ni)
          hbuf[kc * 2 + ni] =
              load16_sc(hp16 + ((mtb * 16 + kc) * 2 + ni) * 64 + lane);
      WAITV(16);                                // first 16 loads (kc 0..7) done
#pragma unroll
      for (int kc = 0; kc < 8; ++kc)
#pragma unroll
        for (int ni = 0; ni < 2; ++ni) {
          short8 b = __builtin_bit_cast(short8, hbuf[kc * 2 + ni]);
#pragma unroll
          for (int mi = 0; mi < 2; ++mi)
            acc[mi][ni] = __builtin_amdgcn_mfma_f32_16x16x32_bf16(bfh[mi][kc], b, acc[mi][ni], 0, 0, 0);
        }
      WAITV(0);                                 // remaining 16 loads done
#pragma unroll
      for (int kc = 8; kc < 16; ++kc)
#pragma unroll
        for (int ni = 0; ni < 2; ++ni) {
          short8 b = __builtin_bit_cast(short8, hbuf[kc * 2 + ni]);
#pragma unroll
          for (int mi = 0; mi < 2; ++mi)
            acc[mi][ni] = __builtin_amdgcn_mfma_f32_16x16x32_bf16(bfh[mi][kc], b, acc[mi][ni], 0, 0, 0);
        }
    }

    // ---- Phase D: lane-local gates (reg=gate), state update, 4B stores ----
    short* hx = hexch + ((size_t)d * TT + t) * 32768;
#pragma unroll
    for (int ni = 0; ni < 2; ++ni) {
      const bool m = (t < Lr[ni]);
      unsigned short hnb[2];
#pragma unroll
      for (int mi = 0; mi < 2; ++mi) {
        f32x4 A = acc[mi][ni];
        float gi = A[0] + b4[mi][0];
        float gf = A[1] + b4[mi][1];
        float gg = A[2] + b4[mi][2];
        float go = A[3] + b4[mi][3];
        float si = sigmoid_f(gi), sf = sigmoid_f(gf), so = sigmoid_f(go);
        float ct = sf * cst[mi][ni] + si * tanh_f(gg);
        float ht = so * tanh_f(ct);
        float cn = m ? ct : cst[mi][ni];
        float hn = m ? ht : hst[mi][ni];
        cst[mi][ni] = cn;
        hst[mi][ni] = hn;
        hnb[mi] = f2bf(hn);                     // frozen carry (= history when t<L)
      }
      // units (ubase+2*lhi, +1) for batch ni*16+l15: one packed 4B store;
      // wave's 64 stores cover one contiguous 256B run of packet (kc_w, ni).
      unsigned int up = ((unsigned int)hnb[1] << 16) | hnb[0];
      store4_sc((char*)hx
                    + (size_t)(((mtb * 16 + kc_w) * 2 + ni) * 64 + lhi_c * 16 + l15) * 16
                    + lhi * 4,
                up);
    }

    // ---- Phase E: ack own h-stores at the coherence point, publish flag ----
    if (lane == 0) {
      int sv = s + 1;
      asm volatile("s_waitcnt vmcnt(0)\n\t"
                   "global_store_dword %0, %1, off sc0 sc1"
                   :: "v"(fl_mine), "v"(sv) : "memory");
    }
  }
}

// ---------------- K2: emission logits = [hf|hb] @ Wfc^T via MFMA ------------
// Reads fragment-packed hexch (frozen values at t>=L are masked by the CRF).
__launch_bounds__(256)
__global__ void emis_kernel(const short* __restrict__ hexch,
                            const short* __restrict__ WfcPack,
                            float* __restrict__ logits) {
  __shared__ short wfc[16 * 1032];             // padded stride vs bank conflicts
  const int tid = threadIdx.x;
  for (int idx = tid; idx < 2048; idx += 256) {
    int n = idx >> 7, c8 = idx & 127;
    short8 v = *reinterpret_cast<const short8*>(WfcPack + n * 1024 + c8 * 8);
    *reinterpret_cast<short8*>(&wfc[n * 1032 + c8 * 8]) = v;
  }
  __syncthreads();
  const int wv = tid >> 6, lane = tid & 63;
  const int l15 = lane & 15, lhi = lane >> 4;
  const i32x4* hx = (const i32x4*)hexch;
#pragma unroll
  for (int mt2 = 0; mt2 < 2; ++mt2) {
    int m = (blockIdx.x * 4 + wv) * 2 + mt2;
    int r0 = m * 16;                           // r = t*64 + b ; block has fixed t
    int t   = r0 >> 6;
    int mtb = (r0 >> 5) & 1;
    int ti  = (r0 >> 4) & 1;
    f32x4 acc = (f32x4){0.f, 0.f, 0.f, 0.f};
#pragma unroll
    for (int kc = 0; kc < 32; ++kc) {
      int dd  = kc >> 4;                       // 0 = forward half, 1 = backward
      int kcf = kc & 15;
      short8 a = __builtin_bit_cast(short8,
          hx[((size_t)dd * TT + t) * 4096 + ((mtb * 16 + kcf) * 2 + ti) * 64
             + lhi * 16 + l15]);
      short8 b = *reinterpret_cast<const short8*>(&wfc[l15 * 1032 + kc * 32 + lhi * 8]);
      acc = __builtin_amdgcn_mfma_f32_16x16x32_bf16(a, b, acc, 0, 0, 0);
    }
    int c = l15;
    if (c < 9) {
#pragma unroll
      for (int reg = 0; reg < 4; ++reg) {
        int rr = r0 + lhi * 4 + reg;
        int b = rr & 63, tt = rr >> 6;
        logits[((size_t)b * TT + tt) * 9 + c] = acc[reg];
      }
    }
  }
}

// ---------------- K3: CRF numerator + forward algorithm per batch -----------
__global__ void crf_kernel(const float* __restrict__ logits, const int* __restrict__ y,
                           const int* __restrict__ seq_len, const float* __restrict__ start_t,
                           const float* __restrict__ end_t, const float* __restrict__ trans,
                           float* __restrict__ partials) {
  const int b = blockIdx.x;
  const int lane = threadIdx.x;          // 64
  const float* lg = logits + (size_t)b * TT * 9;
  const int* yb = y + b * TT;
  const int L = seq_len[b];

  float acc = 0.f;
  for (int t = lane; t < TT; t += 64) {
    if (t < L) {
      float mx = lg[t * 9];
      for (int c = 1; c < 9; ++c) mx = fmaxf(mx, lg[t * 9 + c]);
      float se = 0.f;
      for (int c = 0; c < 9; ++c) se += __expf(lg[t * 9 + c] - mx);
      float lse = mx + __logf(se);
      int yt = yb[t];
      acc += lg[t * 9 + yt] - lse;
      if (t >= 1) acc += trans[yb[t - 1] * 9 + yt];
    }
  }
#pragma unroll
  for (int off = 32; off >= 1; off >>= 1) acc += __shfl_down(acc, off, 64);

  const int c = (lane < 9) ? lane : 0;
  float score;
  {
    float mx = lg[0];
    for (int cc = 1; cc < 9; ++cc) mx = fmaxf(mx, lg[cc]);
    float se = 0.f;
    for (int cc = 0; cc < 9; ++cc) se += __expf(lg[cc] - mx);
    score = start_t[c] + lg[c] - (mx + __logf(se));
  }
  float tr[9];
#pragma unroll
  for (int cc = 0; cc < 9; ++cc) tr[cc] = trans[cc * 9 + c];
  for (int t = 1; t < L; ++t) {
    const float* lt = lg + t * 9;
    float mx2 = lt[0];
    for (int cc = 1; cc < 9; ++cc) mx2 = fmaxf(mx2, lt[cc]);
    float se2 = 0.f;
    for (int cc = 0; cc < 9; ++cc) se2 += __expf(lt[cc] - mx2);
    float em = lt[c] - (mx2 + __logf(se2));
    float vv[9];
    float mx = -1e30f;
#pragma unroll
    for (int cc = 0; cc < 9; ++cc) {
      float sp = __shfl(score, cc, 64);
      vv[cc] = sp + tr[cc];
      mx = fmaxf(mx, vv[cc]);
    }
    float se = 0.f;
#pragma unroll
    for (int cc = 0; cc < 9; ++cc) se += __expf(vv[cc] - mx);
    score = mx + __logf(se) + em;
  }
  float val = (lane < 9) ? (score + end_t[lane]) : -1e30f;
  float mm = val;
#pragma unroll
  for (int off = 1; off < 64; off <<= 1) mm = fmaxf(mm, __shfl_xor(mm, off, 64));
  float se = (lane < 9) ? __expf(val - mm) : 0.f;
#pragma unroll
  for (int off = 1; off < 64; off <<= 1) se += __shfl_xor(se, off, 64);
  float den = mm + __logf(se);
  if (lane == 0) {
    float num = acc + start_t[yb[0]] + end_t[yb[L - 1]];
    partials[b] = num - den;
  }
}

// ---------------- K4: final reduce ------------------------------------------
__global__ void finalize_kernel(const float* __restrict__ partials, float* __restrict__ out) {
  int l = threadIdx.x;
  float v = partials[l];
#pragma unroll
  for (int off = 32; off >= 1; off >>= 1) v += __shfl_down(v, off, 64);
  if (l == 0) out[0] = -v;
}

extern "C" void kernel_launch(void* const* d_in, const int* in_sizes, int n_in,
                              void* d_out, int out_size, void* d_ws, size_t ws_size,
                              hipStream_t stream) {
  const int*   x     = (const int*)d_in[0];
  const int*   seqln = (const int*)d_in[1];
  const int*   y     = (const int*)d_in[2];
  const float* emb   = (const float*)d_in[3];
  const float* Wih_f = (const float*)d_in[4];
  const float* Whh_f = (const float*)d_in[5];
  const float* b_f   = (const float*)d_in[6];
  const float* Wih_b = (const float*)d_in[7];
  const float* Whh_b = (const float*)d_in[8];
  const float* b_b   = (const float*)d_in[9];
  const float* Wfc   = (const float*)d_in[10];
  const float* st    = (const float*)d_in[11];
  const float* en    = (const float*)d_in[12];
  const float* trans = (const float*)d_in[13];
  float* out = (float*)d_out;

  char* ws = (char*)d_ws;                         // total required ~91.4 MB
  short* WpackX   = (short*)(ws + 0);             // 2,097,152
  short* WpackH   = (short*)(ws + 2097152);       // 4,194,304
  short* WfcPack  = (short*)(ws + 6291456);       //    32,768
  short* xpack    = (short*)(ws + 6324224);       // 16,777,216
  int*   flags    = (int*)  (ws + 23101440);      //     1,024
  float* partials = (float*)(ws + 23102464);      //       256
  float* logits   = (float*)(ws + 23102720);      // 1,179,648
  short* hexch    = (short*)(ws + 24282368);      // 67,108,864 -> end 91,391,232

  pack_weights<<<64, 256, 0, stream>>>(Wih_f, Whh_f, Wih_b, Whh_b, Wfc,
                                       WpackX, WpackH, WfcPack);
  pack_x<<<4096, 256, 0, stream>>>(x, emb, xpack);
  init_state<<<1, 256, 0, stream>>>(flags);
  lstm_step_kernel<<<64, 256, 0, stream>>>((const short8*)xpack, WpackX, WpackH,
                                           hexch, flags, b_f, b_b, seqln);
  emis_kernel<<<256, 256, 0, stream>>>(hexch, WfcPack, logits);
  crf_kernel<<<64, 64, 0, stream>>>(logits, y, seqln, st, en, trans, partials);
  finalize_kernel<<<1, 64, 0, stream>>>(partials, out);
}